// Round 1
// baseline (1403.257 us; speedup 1.0000x reference)
//
#include <hip/hip_runtime.h>
#include <hip/hip_bf16.h>
#include <math.h>

#define HEADS 8
#define EPS 1e-5f

// ---------------- CSR build ----------------
__global__ void k_deg(const int* __restrict__ ei, int* __restrict__ deg, int E, int N) {
    int e = blockIdx.x * blockDim.x + threadIdx.x;
    int E2 = E + N;
    if (e >= E2) return;
    int dst = (e < E) ? ei[E + e] : (e - E);
    atomicAdd(&deg[dst], 1);
}

__global__ void k_scan(const int* __restrict__ deg, int* __restrict__ row_ptr, int n) {
    __shared__ int part[1024];
    int t = threadIdx.x;
    int chunk = (n + 1023) >> 10;
    int begin = t * chunk;
    int end = begin + chunk;
    if (begin > n) begin = n;
    if (end > n) end = n;
    int s = 0;
    for (int i = begin; i < end; ++i) s += deg[i];
    part[t] = s;
    __syncthreads();
    for (int off = 1; off < 1024; off <<= 1) {
        int v = (t >= off) ? part[t - off] : 0;
        __syncthreads();
        part[t] += v;
        __syncthreads();
    }
    int run = (t == 0) ? 0 : part[t - 1];
    for (int i = begin; i < end; ++i) { row_ptr[i] = run; run += deg[i]; }
    if (t == 1023) row_ptr[n] = part[1023];
}

__global__ void k_fill(const int* __restrict__ ei, const int* __restrict__ row_ptr,
                       int* __restrict__ fill, int* __restrict__ src_sorted, int E, int N) {
    int e = blockIdx.x * blockDim.x + threadIdx.x;
    int E2 = E + N;
    if (e >= E2) return;
    int srcv, dst;
    if (e < E) { srcv = ei[e]; dst = ei[E + e]; } else { srcv = e - E; dst = srcv; }
    int p = atomicAdd(&fill[dst], 1);
    src_sorted[row_ptr[dst] + p] = srcv;
}

// ---------------- weight reshape: Wp[(h*ci+k)*co + c] = W[k*8co + h*co + c] ----------------
__global__ void k_wt(const float* __restrict__ W, float* __restrict__ Wp, int ci, int co) {
    int idx = blockIdx.x * blockDim.x + threadIdx.x;
    int total = ci * HEADS * co;
    if (idx >= total) return;
    int c = idx % co;
    int rest = idx / co;
    int k = rest % ci;
    int h = rest / ci;
    Wp[idx] = W[k * (HEADS * co) + h * co + c];
}

// ---------------- front: pos BN stats ----------------
__global__ void k_pos_stats(const float* __restrict__ pos, float* __restrict__ stats, int n) {
    int gid = blockIdx.x * blockDim.x + threadIdx.x;
    int stride = gridDim.x * blockDim.x;
    float s0 = 0, s1 = 0, q0 = 0, q1 = 0;
    for (int i = gid; i < n; i += stride) {
        float a = pos[i * 2], b = pos[i * 2 + 1];
        s0 += a; s1 += b; q0 += a * a; q1 += b * b;
    }
    __shared__ float red[256][4];
    int t = threadIdx.x;
    red[t][0] = s0; red[t][1] = s1; red[t][2] = q0; red[t][3] = q1;
    __syncthreads();
    for (int off = 128; off > 0; off >>= 1) {
        if (t < off) {
            red[t][0] += red[t + off][0]; red[t][1] += red[t + off][1];
            red[t][2] += red[t + off][2]; red[t][3] += red[t + off][3];
        }
        __syncthreads();
    }
    if (t == 0) {
        atomicAdd(&stats[0], red[0][0]); atomicAdd(&stats[1], red[0][1]);
        atomicAdd(&stats[2], red[0][2]); atomicAdd(&stats[3], red[0][3]);
    }
}

// ---------------- front: bn(pos) ++ x -> lin0 -> relu ----------------
__global__ void k_front(const float* __restrict__ pos, const float* __restrict__ x,
                        const float* __restrict__ stats, const float* __restrict__ g0,
                        const float* __restrict__ b0, const float* __restrict__ W,
                        const float* __restrict__ bias, float* __restrict__ out, int n) {
    int i = blockIdx.x * blockDim.x + threadIdx.x;
    if (i >= n) return;
    float invn = 1.0f / (float)n;
    float in4[4];
    #pragma unroll
    for (int j = 0; j < 2; ++j) {
        float m = stats[j] * invn;
        float v = stats[2 + j] * invn - m * m;
        in4[j] = (pos[i * 2 + j] - m) * rsqrtf(v + EPS) * g0[j] + b0[j];
    }
    in4[2] = x[i * 2]; in4[3] = x[i * 2 + 1];
    #pragma unroll
    for (int o = 0; o < 16; ++o) {
        float s = bias[o];
        #pragma unroll
        for (int j = 0; j < 4; ++j) s += in4[j] * W[j * 16 + o];
        out[i * 16 + o] = fmaxf(s, 0.f);
    }
}

// ---------------- XU = h @ U  (no +c here; c cancels in src-dst, added in edge kernel) ----------------
__global__ void k_xu(const float* __restrict__ h, const float* __restrict__ U,
                     float* __restrict__ xu, int n, int ci) {
    int idx = blockIdx.x * blockDim.x + threadIdx.x;
    if (idx >= n * HEADS) return;
    int i = idx >> 3, hh = idx & 7;
    const float* hr = h + (size_t)i * ci;
    float s = 0.f;
    for (int k = 0; k < ci; ++k) s += hr[k] * U[k * HEADS + hh];
    xu[idx] = s;
}

// ---------------- edge aggregation: one wave per node ----------------
// S[i, h*ci + k] = (1/deg_i) * sum_{e: dst=i} softmax_h(xu[src]-xu[i]+c)[h] * h_in[src][k]
__global__ __launch_bounds__(64) void k_edge(const float* __restrict__ hin,
                                             const float* __restrict__ xu,
                                             const float* __restrict__ chead,
                                             const int* __restrict__ row_ptr,
                                             const int* __restrict__ src_sorted,
                                             float* __restrict__ S, int n, int ci) {
    int i = blockIdx.x;
    int lane = threadIdx.x;
    int rp0 = row_ptr[i], rp1 = row_ptr[i + 1];
    float xui[HEADS], ch[HEADS];
    #pragma unroll
    for (int hh = 0; hh < HEADS; ++hh) { xui[hh] = xu[i * HEADS + hh]; ch[hh] = chead[hh]; }
    float acc[HEADS][4];
    #pragma unroll
    for (int hh = 0; hh < HEADS; ++hh)
        #pragma unroll
        for (int c = 0; c < 4; ++c) acc[hh][c] = 0.f;
    int cp = (ci + 63) >> 6;
    for (int e = rp0; e < rp1; ++e) {
        int s = src_sorted[e];
        float t[HEADS];
        float mx = -1e30f;
        #pragma unroll
        for (int hh = 0; hh < HEADS; ++hh) {
            t[hh] = xu[s * HEADS + hh] - xui[hh] + ch[hh];
            mx = fmaxf(mx, t[hh]);
        }
        float ssum = 0.f;
        #pragma unroll
        for (int hh = 0; hh < HEADS; ++hh) { t[hh] = __expf(t[hh] - mx); ssum += t[hh]; }
        float qinv = 1.0f / ssum;
        const float* hs = hin + (size_t)s * ci;
        for (int c = 0; c < cp; ++c) {
            int k = lane + (c << 6);
            float xv = (k < ci) ? hs[k] : 0.f;
            #pragma unroll
            for (int hh = 0; hh < HEADS; ++hh) acc[hh][c] += (t[hh] * qinv) * xv;
        }
    }
    float dinv = 1.0f / (float)(rp1 - rp0);
    for (int c = 0; c < cp; ++c) {
        int k = lane + (c << 6);
        if (k < ci) {
            #pragma unroll
            for (int hh = 0; hh < HEADS; ++hh)
                S[(size_t)i * HEADS * ci + hh * ci + k] = acc[hh][c] * dinv;
        }
    }
}

// ---------------- tiled fp32 GEMM: C[M,Ncol] = A[M,K] @ B[K,Ncol] + bias (opt relu) ----------------
#define BM 64
#define BN 64
#define BK 16
__global__ __launch_bounds__(256) void k_gemm(const float* __restrict__ A,
                                              const float* __restrict__ B,
                                              const float* __restrict__ bias,
                                              float* __restrict__ C,
                                              int M, int K, int Ncol, int relu) {
    __shared__ __align__(16) float As[BK][BM + 4];
    __shared__ __align__(16) float Bs[BK][BN + 4];
    int tid = threadIdx.x;
    int tx = tid & 15, ty = tid >> 4;
    int m0 = blockIdx.x * BM, n0 = blockIdx.y * BN;
    float acc[4][4] = {};
    for (int k0 = 0; k0 < K; k0 += BK) {
        #pragma unroll
        for (int l = 0; l < 4; ++l) {
            int e = tid + l * 256;
            int kk = e & 15, row = e >> 4;
            int gm = m0 + row;
            As[kk][row] = (gm < M) ? A[(size_t)gm * K + k0 + kk] : 0.f;
        }
        #pragma unroll
        for (int l = 0; l < 4; ++l) {
            int e = tid + l * 256;
            int nn = e & 63, kk = e >> 6;
            int gn = n0 + nn;
            Bs[kk][nn] = (gn < Ncol) ? B[(size_t)(k0 + kk) * Ncol + gn] : 0.f;
        }
        __syncthreads();
        #pragma unroll
        for (int kk = 0; kk < BK; ++kk) {
            float4 a4 = *reinterpret_cast<const float4*>(&As[kk][ty * 4]);
            float4 b4 = *reinterpret_cast<const float4*>(&Bs[kk][tx * 4]);
            float a[4] = {a4.x, a4.y, a4.z, a4.w};
            float b[4] = {b4.x, b4.y, b4.z, b4.w};
            #pragma unroll
            for (int ii = 0; ii < 4; ++ii)
                #pragma unroll
                for (int jj = 0; jj < 4; ++jj) acc[ii][jj] += a[ii] * b[jj];
        }
        __syncthreads();
    }
    #pragma unroll
    for (int ii = 0; ii < 4; ++ii) {
        int gm = m0 + ty * 4 + ii;
        if (gm >= M) continue;
        #pragma unroll
        for (int jj = 0; jj < 4; ++jj) {
            int gn = n0 + tx * 4 + jj;
            if (gn >= Ncol) continue;
            float v = acc[ii][jj] + bias[gn];
            if (relu) v = fmaxf(v, 0.f);
            C[(size_t)gm * Ncol + gn] = v;
        }
    }
}

// ---------------- BN stats over nodes (co divides 256) ----------------
__global__ void k_stats(const float* __restrict__ z, float* __restrict__ stats, int n, int co) {
    int tid = threadIdx.x;
    long total = (long)n * co;
    long stride = (long)gridDim.x * blockDim.x;   // multiple of 256 -> multiple of co
    long start = (long)blockIdx.x * blockDim.x + tid;
    float s = 0.f, q = 0.f;
    for (long idx = start; idx < total; idx += stride) {
        float v = z[idx];
        s += v; q += v * v;
    }
    __shared__ float ls[256], lq[256];
    ls[tid] = s; lq[tid] = q;
    __syncthreads();
    for (int off = 128; off >= co; off >>= 1) {
        if (tid < off) { ls[tid] += ls[tid + off]; lq[tid] += lq[tid + off]; }
        __syncthreads();
    }
    if (tid < co) {
        atomicAdd(&stats[tid], ls[tid]);
        atomicAdd(&stats[co + tid], lq[tid]);
    }
}

// ---------------- BN apply + relu ----------------
__global__ void k_bnapply(const float* __restrict__ z, const float* __restrict__ stats,
                          const float* __restrict__ g, const float* __restrict__ b,
                          float* __restrict__ out, int n, int co) {
    long idx = (long)blockIdx.x * blockDim.x + threadIdx.x;
    if (idx >= (long)n * co) return;
    int ch = (int)(idx % co);
    float invn = 1.0f / (float)n;
    float m = stats[ch] * invn;
    float v = stats[co + ch] * invn - m * m;
    float r = (z[idx] - m) * rsqrtf(v + EPS) * g[ch] + b[ch];
    out[idx] = fmaxf(r, 0.f);
}

// ---------------- final lin2: [N,64] @ [64,2] + b ----------------
__global__ void k_lin2(const float* __restrict__ h, const float* __restrict__ W,
                       const float* __restrict__ b, float* __restrict__ out, int n) {
    int i = blockIdx.x * blockDim.x + threadIdx.x;
    if (i >= n) return;
    float s0 = b[0], s1 = b[1];
    const float* hr = h + (size_t)i * 64;
    #pragma unroll
    for (int k = 0; k < 64; ++k) {
        float v = hr[k];
        s0 += v * W[k * 2];
        s1 += v * W[k * 2 + 1];
    }
    out[i * 2] = s0;
    out[i * 2 + 1] = s1;
}

extern "C" void kernel_launch(void* const* d_in, const int* in_sizes, int n_in,
                              void* d_out, int out_size, void* d_ws, size_t ws_size,
                              hipStream_t stream) {
    const float* pos    = (const float*)d_in[0];
    const float* x      = (const float*)d_in[1];
    const int*   ei     = (const int*)d_in[2];
    const float* g0     = (const float*)d_in[3];
    const float* b0     = (const float*)d_in[4];
    const float* lin0_W = (const float*)d_in[5];
    const float* lin0_b = (const float*)d_in[6];
    const float* lin1_W = (const float*)d_in[43];
    const float* lin1_b = (const float*)d_in[44];
    const float* lin2_W = (const float*)d_in[45];
    const float* lin2_b = (const float*)d_in[46];

    int N = in_sizes[0] / 2;
    int E = in_sizes[2] / 2;
    int E2 = E + N;

    static const int CI[6] = {16, 32, 64, 128, 256, 128};
    static const int CO[6] = {32, 64, 128, 256, 128, 128};

    // workspace carve (256B aligned regions)
    char* p = (char*)d_ws;
    auto alloc = [&](size_t bytes) -> char* {
        char* r = p;
        p += (bytes + 255) & ~(size_t)255;
        return r;
    };
    float* wp[6];
    for (int i = 0; i < 6; ++i) wp[i] = (float*)alloc((size_t)CI[i] * HEADS * CO[i] * 4);
    int* row_ptr    = (int*)alloc(((size_t)N + 1) * 4);
    int* deg        = (int*)alloc((size_t)N * 4);
    int* fill       = (int*)alloc((size_t)N * 4);
    int* src_sorted = (int*)alloc((size_t)E2 * 4);
    float* xu       = (float*)alloc((size_t)N * HEADS * 4);
    float* S        = (float*)alloc((size_t)N * 2048 * 4);
    float* z        = (float*)alloc((size_t)N * 256 * 4);
    float* hA       = (float*)alloc((size_t)N * 256 * 4);
    float* hB       = (float*)alloc((size_t)N * 256 * 4);
    float* stats    = (float*)alloc(1024 * 4);

    hipMemsetAsync(deg, 0, (size_t)N * 4, stream);
    hipMemsetAsync(fill, 0, (size_t)N * 4, stream);
    hipMemsetAsync(stats, 0, 1024 * 4, stream);

    const int tpb = 256;
    k_deg<<<(E2 + tpb - 1) / tpb, tpb, 0, stream>>>(ei, deg, E, N);
    k_scan<<<1, 1024, 0, stream>>>(deg, row_ptr, N);
    k_fill<<<(E2 + tpb - 1) / tpb, tpb, 0, stream>>>(ei, row_ptr, fill, src_sorted, E, N);
    for (int i = 0; i < 6; ++i) {
        const float* W = (const float*)d_in[7 + i * 6];
        int total = CI[i] * HEADS * CO[i];
        k_wt<<<(total + tpb - 1) / tpb, tpb, 0, stream>>>(W, wp[i], CI[i], CO[i]);
    }
    k_pos_stats<<<64, 256, 0, stream>>>(pos, stats, N);
    k_front<<<(N + tpb - 1) / tpb, tpb, 0, stream>>>(pos, x, stats, g0, b0, lin0_W, lin0_b, hA, N);

    float* hin = hA;
    float* hout = hB;
    for (int L = 0; L < 6; ++L) {
        int ci = CI[L], co = CO[L];
        const float* U  = (const float*)d_in[7 + L * 6 + 1];
        const float* Ch = (const float*)d_in[7 + L * 6 + 2];
        const float* Bb = (const float*)d_in[7 + L * 6 + 3];
        const float* gc = (const float*)d_in[7 + L * 6 + 4];
        const float* bc = (const float*)d_in[7 + L * 6 + 5];

        k_xu<<<(N * HEADS + tpb - 1) / tpb, tpb, 0, stream>>>(hin, U, xu, N, ci);
        k_edge<<<N, 64, 0, stream>>>(hin, xu, Ch, row_ptr, src_sorted, S, N, ci);
        dim3 g((N + BM - 1) / BM, (co + BN - 1) / BN);
        k_gemm<<<g, 256, 0, stream>>>(S, wp[L], Bb, z, N, HEADS * ci, co, 0);
        hipMemsetAsync(stats, 0, (size_t)2 * co * 4, stream);
        k_stats<<<128, 256, 0, stream>>>(z, stats, N, co);
        long tot = (long)N * co;
        k_bnapply<<<(tot + tpb - 1) / tpb, tpb, 0, stream>>>(z, stats, gc, bc, hout, N, co);
        float* t = hin; hin = hout; hout = t;
    }

    dim3 g1((N + BM - 1) / BM, 1);
    k_gemm<<<g1, 256, 0, stream>>>(hin, lin1_W, lin1_b, z, N, 128, 64, 1);
    k_lin2<<<(N + tpb - 1) / tpb, tpb, 0, stream>>>(z, lin2_W, lin2_b, (float*)d_out, N);
}

// Round 2
// 1323.431 us; speedup vs baseline: 1.0603x; 1.0603x over previous
//
#include <hip/hip_runtime.h>
#include <hip/hip_bf16.h>
#include <math.h>

#define HEADS 8
#define EPS 1e-5f

// ---------------- CSR build ----------------
__global__ void k_deg(const int* __restrict__ ei, int* __restrict__ deg, int E, int N) {
    int e = blockIdx.x * blockDim.x + threadIdx.x;
    int E2 = E + N;
    if (e >= E2) return;
    int dst = (e < E) ? ei[E + e] : (e - E);
    atomicAdd(&deg[dst], 1);
}

__global__ void k_scan(const int* __restrict__ deg, int* __restrict__ row_ptr, int n) {
    __shared__ int part[1024];
    int t = threadIdx.x;
    int chunk = (n + 1023) >> 10;
    int begin = t * chunk;
    int end = begin + chunk;
    if (begin > n) begin = n;
    if (end > n) end = n;
    int s = 0;
    for (int i = begin; i < end; ++i) s += deg[i];
    part[t] = s;
    __syncthreads();
    for (int off = 1; off < 1024; off <<= 1) {
        int v = (t >= off) ? part[t - off] : 0;
        __syncthreads();
        part[t] += v;
        __syncthreads();
    }
    int run = (t == 0) ? 0 : part[t - 1];
    for (int i = begin; i < end; ++i) { row_ptr[i] = run; run += deg[i]; }
    if (t == 1023) row_ptr[n] = part[1023];
}

__global__ void k_fill(const int* __restrict__ ei, const int* __restrict__ row_ptr,
                       int* __restrict__ fill, int* __restrict__ src_sorted, int E, int N) {
    int e = blockIdx.x * blockDim.x + threadIdx.x;
    int E2 = E + N;
    if (e >= E2) return;
    int srcv, dst;
    if (e < E) { srcv = ei[e]; dst = ei[E + e]; } else { srcv = e - E; dst = srcv; }
    int p = atomicAdd(&fill[dst], 1);
    src_sorted[row_ptr[dst] + p] = srcv;
}

// ---------------- weight reshape: Wp[(h*ci+k)*co + c] = W[k*8co + h*co + c] ----------------
__global__ void k_wt(const float* __restrict__ W, float* __restrict__ Wp, int ci, int co) {
    int idx = blockIdx.x * blockDim.x + threadIdx.x;
    int total = ci * HEADS * co;
    if (idx >= total) return;
    int c = idx % co;
    int rest = idx / co;
    int k = rest % ci;
    int h = rest / ci;
    Wp[idx] = W[k * (HEADS * co) + h * co + c];
}

// ---------------- front: pos BN stats ----------------
__global__ void k_pos_stats(const float* __restrict__ pos, float* __restrict__ stats, int n) {
    int gid = blockIdx.x * blockDim.x + threadIdx.x;
    int stride = gridDim.x * blockDim.x;
    float s0 = 0, s1 = 0, q0 = 0, q1 = 0;
    for (int i = gid; i < n; i += stride) {
        float a = pos[i * 2], b = pos[i * 2 + 1];
        s0 += a; s1 += b; q0 += a * a; q1 += b * b;
    }
    __shared__ float red[256][4];
    int t = threadIdx.x;
    red[t][0] = s0; red[t][1] = s1; red[t][2] = q0; red[t][3] = q1;
    __syncthreads();
    for (int off = 128; off > 0; off >>= 1) {
        if (t < off) {
            red[t][0] += red[t + off][0]; red[t][1] += red[t + off][1];
            red[t][2] += red[t + off][2]; red[t][3] += red[t + off][3];
        }
        __syncthreads();
    }
    if (t == 0) {
        atomicAdd(&stats[0], red[0][0]); atomicAdd(&stats[1], red[0][1]);
        atomicAdd(&stats[2], red[0][2]); atomicAdd(&stats[3], red[0][3]);
    }
}

// ---------------- front: bn(pos) ++ x -> lin0 -> relu ----------------
__global__ void k_front(const float* __restrict__ pos, const float* __restrict__ x,
                        const float* __restrict__ stats, const float* __restrict__ g0,
                        const float* __restrict__ b0, const float* __restrict__ W,
                        const float* __restrict__ bias, float* __restrict__ out, int n) {
    int i = blockIdx.x * blockDim.x + threadIdx.x;
    if (i >= n) return;
    float invn = 1.0f / (float)n;
    float in4[4];
    #pragma unroll
    for (int j = 0; j < 2; ++j) {
        float m = stats[j] * invn;
        float v = stats[2 + j] * invn - m * m;
        in4[j] = (pos[i * 2 + j] - m) * rsqrtf(v + EPS) * g0[j] + b0[j];
    }
    in4[2] = x[i * 2]; in4[3] = x[i * 2 + 1];
    #pragma unroll
    for (int o = 0; o < 16; ++o) {
        float s = bias[o];
        #pragma unroll
        for (int j = 0; j < 4; ++j) s += in4[j] * W[j * 16 + o];
        out[i * 16 + o] = fmaxf(s, 0.f);
    }
}

// ---------------- XU = h @ U ----------------
__global__ void k_xu(const float* __restrict__ h, const float* __restrict__ U,
                     float* __restrict__ xu, int n, int ci) {
    int idx = blockIdx.x * blockDim.x + threadIdx.x;
    if (idx >= n * HEADS) return;
    int i = idx >> 3, hh = idx & 7;
    const float* hr = h + (size_t)i * ci;
    float s = 0.f;
    for (int k = 0; k < ci; ++k) s += hr[k] * U[k * HEADS + hh];
    xu[idx] = s;
}

// ---------------- edge aggregation: one wave per node ----------------
__global__ __launch_bounds__(64) void k_edge(const float* __restrict__ hin,
                                             const float* __restrict__ xu,
                                             const float* __restrict__ chead,
                                             const int* __restrict__ row_ptr,
                                             const int* __restrict__ src_sorted,
                                             float* __restrict__ S, int n, int ci) {
    int i = blockIdx.x;
    int lane = threadIdx.x;
    int rp0 = row_ptr[i], rp1 = row_ptr[i + 1];
    float xui[HEADS], ch[HEADS];
    #pragma unroll
    for (int hh = 0; hh < HEADS; ++hh) { xui[hh] = xu[i * HEADS + hh]; ch[hh] = chead[hh]; }
    float acc[HEADS][4];
    #pragma unroll
    for (int hh = 0; hh < HEADS; ++hh)
        #pragma unroll
        for (int c = 0; c < 4; ++c) acc[hh][c] = 0.f;
    int cp = (ci + 63) >> 6;
    for (int e = rp0; e < rp1; ++e) {
        int s = src_sorted[e];
        float t[HEADS];
        float mx = -1e30f;
        #pragma unroll
        for (int hh = 0; hh < HEADS; ++hh) {
            t[hh] = xu[s * HEADS + hh] - xui[hh] + ch[hh];
            mx = fmaxf(mx, t[hh]);
        }
        float ssum = 0.f;
        #pragma unroll
        for (int hh = 0; hh < HEADS; ++hh) { t[hh] = __expf(t[hh] - mx); ssum += t[hh]; }
        float qinv = 1.0f / ssum;
        const float* hs = hin + (size_t)s * ci;
        for (int c = 0; c < cp; ++c) {
            int k = lane + (c << 6);
            float xv = (k < ci) ? hs[k] : 0.f;
            #pragma unroll
            for (int hh = 0; hh < HEADS; ++hh) acc[hh][c] += (t[hh] * qinv) * xv;
        }
    }
    float dinv = 1.0f / (float)(rp1 - rp0);
    for (int c = 0; c < cp; ++c) {
        int k = lane + (c << 6);
        if (k < ci) {
            #pragma unroll
            for (int hh = 0; hh < HEADS; ++hh)
                S[(size_t)i * HEADS * ci + hh * ci + k] = acc[hh][c] * dinv;
        }
    }
}

// ---------------- split-K fp32 GEMM: C += A[M,K-chunk] @ B[K-chunk,Ncol] (atomic) ----------------
// grid: (ceil(M/64), ceil(Ncol/64), ksplit). C must be pre-zeroed. No bias (BN absorbs it).
#define BM 64
#define BN 64
#define BK 16
__global__ __launch_bounds__(256, 2) void k_gemm_sk(const float* __restrict__ A,
                                                    const float* __restrict__ B,
                                                    float* __restrict__ C,
                                                    int M, int K, int Ncol, int kchunk) {
    __shared__ __align__(16) float As[2][BK][BM + 4];
    __shared__ __align__(16) float Bs[2][BK][BN + 4];
    int tid = threadIdx.x;
    int m0 = blockIdx.x * BM, n0 = blockIdx.y * BN;
    int kb = blockIdx.z * kchunk;
    int nk = kchunk / BK;           // kchunk always a multiple of BK, K a multiple of kchunk

    // A tile load map: each thread one float4 along K. row 0..63, kk group 0..3
    int arow = tid >> 2;
    int aj = (tid & 3) * 4;
    int gm = m0 + arow;
    bool avalid = gm < M;
    const float* Aptr = A + (size_t)gm * K + kb + aj;

    // B tile load map: each thread one float4 along N. kk 0..15, nn group 0..15
    int bkk = tid >> 4;
    int bnn = (tid & 15) * 4;
    bool bvalid = (n0 + bnn) < Ncol;
    const float* Bptr = B + (size_t)(kb + bkk) * Ncol + n0 + bnn;

    int tx = tid & 15, ty = tid >> 4;
    float acc[4][4] = {};

    float4 zero4 = {0.f, 0.f, 0.f, 0.f};
    float4 aR = avalid ? *(const float4*)Aptr : zero4;
    float4 bR = bvalid ? *(const float4*)Bptr : zero4;
    As[0][aj + 0][arow] = aR.x;
    As[0][aj + 1][arow] = aR.y;
    As[0][aj + 2][arow] = aR.z;
    As[0][aj + 3][arow] = aR.w;
    *(float4*)&Bs[0][bkk][bnn] = bR;

    for (int t = 0; t < nk; ++t) {
        int buf = t & 1;
        __syncthreads();
        float4 aN = zero4, bN = zero4;
        bool have = (t + 1 < nk);
        if (have) {
            if (avalid) aN = *(const float4*)(Aptr + (t + 1) * BK);
            if (bvalid) bN = *(const float4*)(Bptr + (size_t)(t + 1) * BK * Ncol);
        }
        #pragma unroll
        for (int kk = 0; kk < BK; ++kk) {
            float4 a4 = *(const float4*)&As[buf][kk][ty * 4];
            float4 b4 = *(const float4*)&Bs[buf][kk][tx * 4];
            float a[4] = {a4.x, a4.y, a4.z, a4.w};
            float b[4] = {b4.x, b4.y, b4.z, b4.w};
            #pragma unroll
            for (int ii = 0; ii < 4; ++ii)
                #pragma unroll
                for (int jj = 0; jj < 4; ++jj) acc[ii][jj] += a[ii] * b[jj];
        }
        if (have) {
            int nb = buf ^ 1;
            As[nb][aj + 0][arow] = aN.x;
            As[nb][aj + 1][arow] = aN.y;
            As[nb][aj + 2][arow] = aN.z;
            As[nb][aj + 3][arow] = aN.w;
            *(float4*)&Bs[nb][bkk][bnn] = bN;
        }
    }

    #pragma unroll
    for (int ii = 0; ii < 4; ++ii) {
        int gm2 = m0 + ty * 4 + ii;
        if (gm2 >= M) continue;
        #pragma unroll
        for (int jj = 0; jj < 4; ++jj) {
            int gn = n0 + tx * 4 + jj;
            if (gn >= Ncol) continue;
            atomicAdd(&C[(size_t)gm2 * Ncol + gn], acc[ii][jj]);
        }
    }
}

// ---------------- BN stats over nodes (co divides 256) ----------------
__global__ void k_stats(const float* __restrict__ z, float* __restrict__ stats, int n, int co) {
    int tid = threadIdx.x;
    long total = (long)n * co;
    long stride = (long)gridDim.x * blockDim.x;
    long start = (long)blockIdx.x * blockDim.x + tid;
    float s = 0.f, q = 0.f;
    for (long idx = start; idx < total; idx += stride) {
        float v = z[idx];
        s += v; q += v * v;
    }
    __shared__ float ls[256], lq[256];
    ls[tid] = s; lq[tid] = q;
    __syncthreads();
    for (int off = 128; off >= co; off >>= 1) {
        if (tid < off) { ls[tid] += ls[tid + off]; lq[tid] += lq[tid + off]; }
        __syncthreads();
    }
    if (tid < co) {
        atomicAdd(&stats[tid], ls[tid]);
        atomicAdd(&stats[co + tid], lq[tid]);
    }
}

// ---------------- BN apply + relu (float4) ----------------
__global__ void k_bnapply(const float* __restrict__ z, const float* __restrict__ stats,
                          const float* __restrict__ g, const float* __restrict__ b,
                          float* __restrict__ out, int n, int co) {
    long idx4 = (long)blockIdx.x * blockDim.x + threadIdx.x;
    long total4 = (long)n * co / 4;
    if (idx4 >= total4) return;
    float invn = 1.0f / (float)n;
    int c0 = (int)((idx4 * 4) % co);
    float4 zv = *(const float4*)(z + idx4 * 4);
    float r[4] = {zv.x, zv.y, zv.z, zv.w};
    float4 ov;
    float* o = (float*)&ov;
    #pragma unroll
    for (int j = 0; j < 4; ++j) {
        int ch = c0 + j;
        float m = stats[ch] * invn;
        float v = stats[co + ch] * invn - m * m;
        float t = (r[j] - m) * rsqrtf(v + EPS) * g[ch] + b[ch];
        o[j] = fmaxf(t, 0.f);
    }
    *(float4*)(((float*)out) + idx4 * 4) = ov;
}

// ---------------- fused lin1(relu) + lin2: one wave per node ----------------
__global__ __launch_bounds__(256) void k_lin12(const float* __restrict__ h,
                                               const float* __restrict__ W1,
                                               const float* __restrict__ b1,
                                               const float* __restrict__ W2,
                                               const float* __restrict__ b2,
                                               float* __restrict__ out, int n) {
    int lane = threadIdx.x & 63;
    int node = blockIdx.x * 4 + (threadIdx.x >> 6);
    if (node >= n) return;
    const float* hr = h + (size_t)node * 128;
    float s = b1[lane];
    #pragma unroll 8
    for (int k = 0; k < 128; ++k) s += hr[k] * W1[k * 64 + lane];
    float r = fmaxf(s, 0.f);
    float p0 = r * W2[lane * 2];
    float p1 = r * W2[lane * 2 + 1];
    #pragma unroll
    for (int off = 32; off > 0; off >>= 1) {
        p0 += __shfl_down(p0, off, 64);
        p1 += __shfl_down(p1, off, 64);
    }
    if (lane == 0) {
        out[node * 2] = p0 + b2[0];
        out[node * 2 + 1] = p1 + b2[1];
    }
}

extern "C" void kernel_launch(void* const* d_in, const int* in_sizes, int n_in,
                              void* d_out, int out_size, void* d_ws, size_t ws_size,
                              hipStream_t stream) {
    const float* pos    = (const float*)d_in[0];
    const float* x      = (const float*)d_in[1];
    const int*   ei     = (const int*)d_in[2];
    const float* g0     = (const float*)d_in[3];
    const float* b0     = (const float*)d_in[4];
    const float* lin0_W = (const float*)d_in[5];
    const float* lin0_b = (const float*)d_in[6];
    const float* lin1_W = (const float*)d_in[43];
    const float* lin1_b = (const float*)d_in[44];
    const float* lin2_W = (const float*)d_in[45];
    const float* lin2_b = (const float*)d_in[46];

    int N = in_sizes[0] / 2;
    int E = in_sizes[2] / 2;
    int E2 = E + N;

    static const int CI[6] = {16, 32, 64, 128, 256, 128};
    static const int CO[6] = {32, 64, 128, 256, 128, 128};
    static const int KS[6] = {8, 8, 4, 2, 4, 4};   // split-K factors -> ~1256 blocks each

    char* p = (char*)d_ws;
    auto alloc = [&](size_t bytes) -> char* {
        char* r = p;
        p += (bytes + 255) & ~(size_t)255;
        return r;
    };
    float* wp[6];
    for (int i = 0; i < 6; ++i) wp[i] = (float*)alloc((size_t)CI[i] * HEADS * CO[i] * 4);
    int* row_ptr    = (int*)alloc(((size_t)N + 1) * 4);
    int* deg        = (int*)alloc((size_t)N * 4);
    int* fill       = (int*)alloc((size_t)N * 4);
    int* src_sorted = (int*)alloc((size_t)E2 * 4);
    float* xu       = (float*)alloc((size_t)N * HEADS * 4);
    float* S        = (float*)alloc((size_t)N * 2048 * 4);
    float* z        = (float*)alloc((size_t)N * 256 * 4);
    float* hA       = (float*)alloc((size_t)N * 256 * 4);
    float* hB       = (float*)alloc((size_t)N * 256 * 4);
    float* stats    = (float*)alloc(1024 * 4);

    hipMemsetAsync(deg, 0, (size_t)N * 4, stream);
    hipMemsetAsync(fill, 0, (size_t)N * 4, stream);
    hipMemsetAsync(stats, 0, 1024 * 4, stream);

    const int tpb = 256;
    k_deg<<<(E2 + tpb - 1) / tpb, tpb, 0, stream>>>(ei, deg, E, N);
    k_scan<<<1, 1024, 0, stream>>>(deg, row_ptr, N);
    k_fill<<<(E2 + tpb - 1) / tpb, tpb, 0, stream>>>(ei, row_ptr, fill, src_sorted, E, N);
    for (int i = 0; i < 6; ++i) {
        const float* W = (const float*)d_in[7 + i * 6];
        int total = CI[i] * HEADS * CO[i];
        k_wt<<<(total + tpb - 1) / tpb, tpb, 0, stream>>>(W, wp[i], CI[i], CO[i]);
    }
    k_pos_stats<<<64, 256, 0, stream>>>(pos, stats, N);
    k_front<<<(N + tpb - 1) / tpb, tpb, 0, stream>>>(pos, x, stats, g0, b0, lin0_W, lin0_b, hA, N);

    float* hin = hA;
    float* hout = hB;
    for (int L = 0; L < 6; ++L) {
        int ci = CI[L], co = CO[L];
        const float* U  = (const float*)d_in[7 + L * 6 + 1];
        const float* Ch = (const float*)d_in[7 + L * 6 + 2];
        const float* gc = (const float*)d_in[7 + L * 6 + 4];
        const float* bc = (const float*)d_in[7 + L * 6 + 5];
        int K = HEADS * ci;

        k_xu<<<(N * HEADS + tpb - 1) / tpb, tpb, 0, stream>>>(hin, U, xu, N, ci);
        k_edge<<<N, 64, 0, stream>>>(hin, xu, Ch, row_ptr, src_sorted, S, N, ci);

        hipMemsetAsync(z, 0, (size_t)N * co * 4, stream);
        dim3 g((N + BM - 1) / BM, (co + BN - 1) / BN, KS[L]);
        k_gemm_sk<<<g, 256, 0, stream>>>(S, wp[L], z, N, K, co, K / KS[L]);

        hipMemsetAsync(stats, 0, (size_t)2 * co * 4, stream);
        k_stats<<<128, 256, 0, stream>>>(z, stats, N, co);
        long tot4 = (long)N * co / 4;
        k_bnapply<<<(int)((tot4 + tpb - 1) / tpb), tpb, 0, stream>>>(z, stats, gc, bc, hout, N, co);
        float* t = hin; hin = hout; hout = t;
    }

    k_lin12<<<(N + 3) / 4, 256, 0, stream>>>(hin, lin1_W, lin1_b, lin2_W, lin2_b, (float*)d_out, N);
}

// Round 4
// 657.282 us; speedup vs baseline: 2.1349x; 2.0135x over previous
//
#include <hip/hip_runtime.h>
#include <hip/hip_bf16.h>
#include <math.h>

#define HEADS 8
#define EPS 1e-5f

typedef __attribute__((ext_vector_type(8))) _Float16 half8;
typedef __attribute__((ext_vector_type(4))) float f32x4;

__device__ __forceinline__ unsigned short f2h(float f) {
    union { _Float16 h; unsigned short u; } v;
    v.h = (_Float16)f;
    return v.u;
}

// ---------------- CSR build ----------------
__global__ void k_deg(const int* __restrict__ ei, int* __restrict__ deg, int E, int N) {
    int e = blockIdx.x * blockDim.x + threadIdx.x;
    int E2 = E + N;
    if (e >= E2) return;
    int dst = (e < E) ? ei[E + e] : (e - E);
    atomicAdd(&deg[dst], 1);
}

__global__ void k_scan(const int* __restrict__ deg, int* __restrict__ row_ptr, int n) {
    __shared__ int part[1024];
    int t = threadIdx.x;
    int chunk = (n + 1023) >> 10;
    int begin = t * chunk;
    int end = begin + chunk;
    if (begin > n) begin = n;
    if (end > n) end = n;
    int s = 0;
    for (int i = begin; i < end; ++i) s += deg[i];
    part[t] = s;
    __syncthreads();
    for (int off = 1; off < 1024; off <<= 1) {
        int v = (t >= off) ? part[t - off] : 0;
        __syncthreads();
        part[t] += v;
        __syncthreads();
    }
    int run = (t == 0) ? 0 : part[t - 1];
    for (int i = begin; i < end; ++i) { row_ptr[i] = run; run += deg[i]; }
    if (t == 1023) row_ptr[n] = part[1023];
}

__global__ void k_fill(const int* __restrict__ ei, const int* __restrict__ row_ptr,
                       int* __restrict__ fill, int* __restrict__ src_sorted, int E, int N) {
    int e = blockIdx.x * blockDim.x + threadIdx.x;
    int E2 = E + N;
    if (e >= E2) return;
    int srcv, dst;
    if (e < E) { srcv = ei[e]; dst = ei[E + e]; } else { srcv = e - E; dst = srcv; }
    int p = atomicAdd(&fill[dst], 1);
    src_sorted[row_ptr[dst] + p] = srcv;
}

// ---------------- pack all 6 layers' W into MFMA B-fragment order (fp16) ----------------
// Bp[L] layout: [K/32][coP/16][lane 0..63][j 0..7], value = W'[kt*32+(lane>>4)*8+j][nt*16+(lane&15)]
// where W'[h*ci+k][c] = W[k*(8co) + h*co + c]; zero-pad c >= co.
__global__ void k_pack(const float* __restrict__ W0, const float* __restrict__ W1,
                       const float* __restrict__ W2, const float* __restrict__ W3,
                       const float* __restrict__ W4, const float* __restrict__ W5,
                       unsigned short* __restrict__ Bp) {
    int idx = blockIdx.x * blockDim.x + threadIdx.x;
    const int CI[6]  = {16, 32, 64, 128, 256, 128};
    const int CO[6]  = {32, 64, 128, 256, 128, 128};
    const int COP[6] = {64, 64, 128, 256, 128, 128};
    const int OFF[7] = {0, 8192, 24576, 90112, 352256, 614400, 745472};
    if (idx >= OFF[6]) return;
    int L = 0;
    while (idx >= OFF[L + 1]) ++L;
    const float* W = L == 0 ? W0 : L == 1 ? W1 : L == 2 ? W2 : L == 3 ? W3 : L == 4 ? W4 : W5;
    int rel = idx - OFF[L];
    int j = rel & 7;
    int lane = (rel >> 3) & 63;
    int t = rel >> 9;
    int nT = COP[L] >> 4;
    int nt = t % nT, kt = t / nT;
    int kk = kt * 32 + ((lane >> 4) << 3) + j;
    int c  = (nt << 4) + (lane & 15);
    int ci = CI[L], co = CO[L];
    float v = 0.f;
    if (c < co) {
        int h = kk / ci, ko = kk % ci;
        v = W[ko * (HEADS * co) + h * co + c];
    }
    Bp[idx] = f2h(v);
}

// ---------------- front: pos BN stats ----------------
__global__ void k_pos_stats(const float* __restrict__ pos, float* __restrict__ stats, int n) {
    int gid = blockIdx.x * blockDim.x + threadIdx.x;
    int stride = gridDim.x * blockDim.x;
    float s0 = 0, s1 = 0, q0 = 0, q1 = 0;
    for (int i = gid; i < n; i += stride) {
        float a = pos[i * 2], b = pos[i * 2 + 1];
        s0 += a; s1 += b; q0 += a * a; q1 += b * b;
    }
    __shared__ float red[256][4];
    int t = threadIdx.x;
    red[t][0] = s0; red[t][1] = s1; red[t][2] = q0; red[t][3] = q1;
    __syncthreads();
    for (int off = 128; off > 0; off >>= 1) {
        if (t < off) {
            red[t][0] += red[t + off][0]; red[t][1] += red[t + off][1];
            red[t][2] += red[t + off][2]; red[t][3] += red[t + off][3];
        }
        __syncthreads();
    }
    if (t == 0) {
        atomicAdd(&stats[0], red[0][0]); atomicAdd(&stats[1], red[0][1]);
        atomicAdd(&stats[2], red[0][2]); atomicAdd(&stats[3], red[0][3]);
    }
}

// ---------------- front: bn(pos) ++ x -> lin0 -> relu -> h0, plus xu0 = h0 @ U0 ----------------
__global__ void k_front(const float* __restrict__ pos, const float* __restrict__ x,
                        const float* __restrict__ stats, const float* __restrict__ g0,
                        const float* __restrict__ b0, const float* __restrict__ W,
                        const float* __restrict__ bias, const float* __restrict__ U0,
                        float* __restrict__ out, float* __restrict__ xu0, int n) {
    int i = blockIdx.x * blockDim.x + threadIdx.x;
    if (i >= n) return;
    float invn = 1.0f / (float)n;
    float in4[4];
    #pragma unroll
    for (int j = 0; j < 2; ++j) {
        float m = stats[j] * invn;
        float v = stats[2 + j] * invn - m * m;
        in4[j] = (pos[i * 2 + j] - m) * rsqrtf(v + EPS) * g0[j] + b0[j];
    }
    in4[2] = x[i * 2]; in4[3] = x[i * 2 + 1];
    float o16[16];
    #pragma unroll
    for (int o = 0; o < 16; ++o) {
        float s = bias[o];
        #pragma unroll
        for (int j = 0; j < 4; ++j) s += in4[j] * W[j * 16 + o];
        o16[o] = fmaxf(s, 0.f);
        out[i * 16 + o] = o16[o];
    }
    #pragma unroll
    for (int hh = 0; hh < 8; ++hh) {
        float p = 0.f;
        #pragma unroll
        for (int k = 0; k < 16; ++k) p += o16[k] * U0[k * 8 + hh];
        xu0[i * 8 + hh] = p;
    }
}

// ---------------- edge aggregation: one wave per node, vectorized, fp16 S out ----------------
template<int V>
__global__ __launch_bounds__(64) void k_edge_t(const float* __restrict__ hin,
        const float* __restrict__ xu, const float* __restrict__ chead,
        const int* __restrict__ row_ptr, const int* __restrict__ srcs,
        unsigned short* __restrict__ S, int n, int ci) {
    int i = blockIdx.x;
    int lane = threadIdx.x;
    int rp0 = row_ptr[i], rp1 = row_ptr[i + 1];
    float xui[8], ch[8];
    #pragma unroll
    for (int hh = 0; hh < 8; ++hh) { xui[hh] = xu[i * 8 + hh]; ch[hh] = chead[hh]; }
    float acc[8][V];
    #pragma unroll
    for (int hh = 0; hh < 8; ++hh)
        #pragma unroll
        for (int v = 0; v < V; ++v) acc[hh][v] = 0.f;
    int kb = lane * V;
    bool act = kb < ci;
    for (int e = rp0; e < rp1; ++e) {
        int s = srcs[e];
        float t[8], mx = -1e30f;
        #pragma unroll
        for (int hh = 0; hh < 8; ++hh) {
            t[hh] = xu[s * 8 + hh] - xui[hh] + ch[hh];
            mx = fmaxf(mx, t[hh]);
        }
        float ssum = 0.f;
        #pragma unroll
        for (int hh = 0; hh < 8; ++hh) { t[hh] = __expf(t[hh] - mx); ssum += t[hh]; }
        float qinv = 1.f / ssum;
        float xv[V];
        if (act) {
            const float* hs = hin + (size_t)s * ci + kb;
            if (V == 4) { float4 f = *(const float4*)hs; xv[0] = f.x; xv[1] = f.y; xv[2] = f.z; xv[3] = f.w; }
            else if (V == 2) { float2 f = *(const float2*)hs; xv[0] = f.x; xv[1] = f.y; }
            else xv[0] = hs[0];
        } else {
            #pragma unroll
            for (int v = 0; v < V; ++v) xv[v] = 0.f;
        }
        #pragma unroll
        for (int hh = 0; hh < 8; ++hh) {
            float q = t[hh] * qinv;
            #pragma unroll
            for (int v = 0; v < V; ++v) acc[hh][v] += q * xv[v];
        }
    }
    float dinv = 1.f / (float)(rp1 - rp0);
    if (act) {
        #pragma unroll
        for (int hh = 0; hh < 8; ++hh) {
            unsigned short o[V];
            #pragma unroll
            for (int v = 0; v < V; ++v) o[v] = f2h(acc[hh][v] * dinv);
            unsigned short* sp = S + (size_t)i * 8 * ci + hh * ci + kb;
            if (V == 4)      *(ushort4*)sp = *(ushort4*)o;
            else if (V == 2) *(ushort2*)sp = *(ushort2*)o;
            else             sp[0] = o[0];
        }
    }
}

// ---------------- MFMA fp16 GEMM: C[M,co] (+)= S[M,K] @ Wpacked, LDS-free ----------------
// block = 4 waves; wave w: rows m0+16w..+15, cols n0..n0+63 via 4 col-tiles of 16
__global__ __launch_bounds__(256) void k_gemm_mfma(const unsigned short* __restrict__ A,
        const unsigned short* __restrict__ Bp, float* __restrict__ C,
        int M, int K, int co, int nT, int kchunk, int atom) {
    int tid = threadIdx.x;
    int w = tid >> 6, lane = tid & 63;
    int quad = lane >> 4, l16 = lane & 15;
    int m0 = blockIdx.x * 64, n0 = blockIdx.y * 64;
    int kb = blockIdx.z * kchunk;
    int m = m0 + w * 16 + l16;
    int mc = m < M ? m : M - 1;
    const half8* Ap = (const half8*)(A + (size_t)mc * K + kb) + quad;
    const half8* Bb = (const half8*)Bp;
    int nt0 = n0 >> 4;
    int kt0 = kb >> 5;
    f32x4 acc[4] = {};
    int nsteps = kchunk >> 5;
    for (int ks = 0; ks < nsteps; ++ks) {
        half8 a = Ap[ks * 4];
        long bbase = ((long)(kt0 + ks) * nT + nt0) * 64 + lane;
        #pragma unroll
        for (int ct = 0; ct < 4; ++ct) {
            half8 b = Bb[bbase + ct * 64];
            acc[ct] = __builtin_amdgcn_mfma_f32_16x16x32_f16(a, b, acc[ct], 0, 0, 0);
        }
    }
    #pragma unroll
    for (int ct = 0; ct < 4; ++ct) {
        #pragma unroll
        for (int r = 0; r < 4; ++r) {
            int row = m0 + w * 16 + quad * 4 + r;
            int col = n0 + ct * 16 + l16;
            if (row < M && col < co) {
                if (atom) atomicAdd(&C[(size_t)row * co + col], acc[ct][r]);
                else C[(size_t)row * co + col] = acc[ct][r];
            }
        }
    }
}

// ---------------- BN stats over nodes (co divides 256, or co==256) ----------------
__global__ void k_stats(const float* __restrict__ z, float* __restrict__ stats, int n, int co) {
    int tid = threadIdx.x;
    long total = (long)n * co;
    long stride = (long)gridDim.x * blockDim.x;
    long start = (long)blockIdx.x * blockDim.x + tid;
    float s = 0.f, q = 0.f;
    for (long idx = start; idx < total; idx += stride) {
        float v = z[idx];
        s += v; q += v * v;
    }
    __shared__ float ls[256], lq[256];
    ls[tid] = s; lq[tid] = q;
    __syncthreads();
    for (int off = 128; off >= co; off >>= 1) {
        if (tid < off) { ls[tid] += ls[tid + off]; lq[tid] += lq[tid + off]; }
        __syncthreads();
    }
    if (tid < co) {
        atomicAdd(&stats[tid], ls[tid]);
        atomicAdd(&stats[co + tid], lq[tid]);
    }
}

// ---------------- fused BN apply + relu + next-layer xu (wave per node) ----------------
template<int V>
__global__ __launch_bounds__(256) void k_bnx(const float* __restrict__ z,
        const float* __restrict__ stats, const float* __restrict__ g,
        const float* __restrict__ b, const float* __restrict__ Un,
        float* __restrict__ hout, float* __restrict__ xun, int n, int co) {
    int w = threadIdx.x >> 6, lane = threadIdx.x & 63;
    int node = blockIdx.x * 4 + w;
    if (node >= n) return;
    int c0 = lane * V;
    bool act = c0 < co;
    float invn = 1.f / (float)n;
    float hv[V];
    #pragma unroll
    for (int v = 0; v < V; ++v) hv[v] = 0.f;
    if (act) {
        const float* zp = z + (size_t)node * co + c0;
        float zv[V];
        if (V == 4) { float4 f = *(const float4*)zp; zv[0] = f.x; zv[1] = f.y; zv[2] = f.z; zv[3] = f.w; }
        else if (V == 2) { float2 f = *(const float2*)zp; zv[0] = f.x; zv[1] = f.y; }
        else zv[0] = zp[0];
        #pragma unroll
        for (int v = 0; v < V; ++v) {
            int cch = c0 + v;
            float mm = stats[cch] * invn;
            float vr = stats[co + cch] * invn - mm * mm;
            hv[v] = fmaxf((zv[v] - mm) * rsqrtf(vr + EPS) * g[cch] + b[cch], 0.f);
        }
        float* hp = hout + (size_t)node * co + c0;
        if (V == 4) { float4 f = {hv[0], hv[1], hv[2], hv[3]}; *(float4*)hp = f; }
        else if (V == 2) { float2 f = {hv[0], hv[1]}; *(float2*)hp = f; }
        else hp[0] = hv[0];
    }
    if (Un) {
        float p[8];
        #pragma unroll
        for (int hh = 0; hh < 8; ++hh) p[hh] = 0.f;
        if (act) {
            #pragma unroll
            for (int v = 0; v < V; ++v)
                #pragma unroll
                for (int hh = 0; hh < 8; ++hh) p[hh] += hv[v] * Un[(c0 + v) * 8 + hh];
        }
        #pragma unroll
        for (int hh = 0; hh < 8; ++hh) {
            #pragma unroll
            for (int off = 32; off; off >>= 1) p[hh] += __shfl_xor(p[hh], off, 64);
        }
        float mine = 0.f;
        #pragma unroll
        for (int hh = 0; hh < 8; ++hh) if (lane == hh) mine = p[hh];
        if (lane < 8) xun[node * 8 + lane] = mine;
    }
}

// ---------------- fused lin1(relu) + lin2: one wave per node ----------------
__global__ __launch_bounds__(256) void k_lin12(const float* __restrict__ h,
                                               const float* __restrict__ W1,
                                               const float* __restrict__ b1,
                                               const float* __restrict__ W2,
                                               const float* __restrict__ b2,
                                               float* __restrict__ out, int n) {
    int lane = threadIdx.x & 63;
    int node = blockIdx.x * 4 + (threadIdx.x >> 6);
    if (node >= n) return;
    const float* hr = h + (size_t)node * 128;
    float s = b1[lane];
    #pragma unroll 8
    for (int k = 0; k < 128; ++k) s += hr[k] * W1[k * 64 + lane];
    float r = fmaxf(s, 0.f);
    float p0 = r * W2[lane * 2];
    float p1 = r * W2[lane * 2 + 1];
    #pragma unroll
    for (int off = 32; off > 0; off >>= 1) {
        p0 += __shfl_down(p0, off, 64);
        p1 += __shfl_down(p1, off, 64);
    }
    if (lane == 0) {
        out[node * 2] = p0 + b2[0];
        out[node * 2 + 1] = p1 + b2[1];
    }
}

extern "C" void kernel_launch(void* const* d_in, const int* in_sizes, int n_in,
                              void* d_out, int out_size, void* d_ws, size_t ws_size,
                              hipStream_t stream) {
    const float* pos    = (const float*)d_in[0];
    const float* x      = (const float*)d_in[1];
    const int*   ei     = (const int*)d_in[2];
    const float* g0     = (const float*)d_in[3];
    const float* b0     = (const float*)d_in[4];
    const float* lin0_W = (const float*)d_in[5];
    const float* lin0_b = (const float*)d_in[6];
    const float* lin1_W = (const float*)d_in[43];
    const float* lin1_b = (const float*)d_in[44];
    const float* lin2_W = (const float*)d_in[45];
    const float* lin2_b = (const float*)d_in[46];

    int N = in_sizes[0] / 2;
    int E = in_sizes[2] / 2;
    int E2 = E + N;

    static const int CI[6]  = {16, 32, 64, 128, 256, 128};
    static const int CO[6]  = {32, 64, 128, 256, 128, 128};
    static const int COP[6] = {64, 64, 128, 256, 128, 128};
    static const int KS[6]  = {4, 4, 2, 1, 2, 2};
    static const int BPOFF[6] = {0, 8192, 24576, 90112, 352256, 614400};

    char* p = (char*)d_ws;
    auto alloc = [&](size_t bytes) -> char* {
        char* r = p;
        p += (bytes + 255) & ~(size_t)255;
        return r;
    };
    unsigned short* BpAll = (unsigned short*)alloc(745472ull * 2);
    // single zeroed region: deg[N] fill[N] pos4[4] stats6[6*512]
    char* zr = alloc(((size_t)2 * N + 4 + 6 * 512) * 4);
    int*   deg      = (int*)zr;
    int*   fill     = deg + N;
    float* pstats   = (float*)(fill + N);
    float* statsAll = pstats + 4;
    size_t zr_bytes = ((size_t)2 * N + 4 + 6 * 512) * 4;

    int* row_ptr    = (int*)alloc(((size_t)N + 1) * 4);
    int* src_sorted = (int*)alloc((size_t)E2 * 4);
    float* xu       = (float*)alloc((size_t)N * 8 * 4);
    unsigned short* S = (unsigned short*)alloc((size_t)N * 2048 * 2);
    float* z        = (float*)alloc((size_t)N * 256 * 4);
    float* hA       = (float*)alloc((size_t)N * 256 * 4);
    float* hB       = (float*)alloc((size_t)N * 256 * 4);

    hipMemsetAsync(zr, 0, zr_bytes, stream);

    const int tpb = 256;
    k_deg<<<(E2 + tpb - 1) / tpb, tpb, 0, stream>>>(ei, deg, E, N);
    k_scan<<<1, 1024, 0, stream>>>(deg, row_ptr, N);
    k_fill<<<(E2 + tpb - 1) / tpb, tpb, 0, stream>>>(ei, row_ptr, fill, src_sorted, E, N);
    k_pack<<<(745472 + tpb - 1) / tpb, tpb, 0, stream>>>(
        (const float*)d_in[7], (const float*)d_in[13], (const float*)d_in[19],
        (const float*)d_in[25], (const float*)d_in[31], (const float*)d_in[37], BpAll);
    k_pos_stats<<<64, 256, 0, stream>>>(pos, pstats, N);
    k_front<<<(N + tpb - 1) / tpb, tpb, 0, stream>>>(pos, x, pstats, g0, b0, lin0_W, lin0_b,
                                                     (const float*)d_in[8], hA, xu, N);

    float* hin = hA;
    float* hout = hB;
    for (int L = 0; L < 6; ++L) {
        int ci = CI[L], co = CO[L], coP = COP[L];
        const float* Ch = (const float*)d_in[7 + L * 6 + 2];
        const float* gc = (const float*)d_in[7 + L * 6 + 4];
        const float* bc = (const float*)d_in[7 + L * 6 + 5];
        const float* Un = (L < 5) ? (const float*)d_in[7 + (L + 1) * 6 + 1] : nullptr;
        int K = HEADS * ci;
        float* statsL = statsAll + L * 512;

        if (ci >= 256)      k_edge_t<4><<<N, 64, 0, stream>>>(hin, xu, Ch, row_ptr, src_sorted, S, N, ci);
        else if (ci >= 128) k_edge_t<2><<<N, 64, 0, stream>>>(hin, xu, Ch, row_ptr, src_sorted, S, N, ci);
        else                k_edge_t<1><<<N, 64, 0, stream>>>(hin, xu, Ch, row_ptr, src_sorted, S, N, ci);

        int atom = KS[L] > 1;
        if (atom) hipMemsetAsync(z, 0, (size_t)N * co * 4, stream);
        dim3 g((N + 63) / 64, coP / 64, KS[L]);
        k_gemm_mfma<<<g, 256, 0, stream>>>(S, BpAll + BPOFF[L], z, N, K, co, coP / 16, K / KS[L], atom);

        k_stats<<<256, 256, 0, stream>>>(z, statsL, N, co);

        int bgrid = (N + 3) / 4;
        if (co >= 256)      k_bnx<4><<<bgrid, 256, 0, stream>>>(z, statsL, gc, bc, Un, hout, xu, N, co);
        else if (co >= 128) k_bnx<2><<<bgrid, 256, 0, stream>>>(z, statsL, gc, bc, Un, hout, xu, N, co);
        else                k_bnx<1><<<bgrid, 256, 0, stream>>>(z, statsL, gc, bc, Un, hout, xu, N, co);

        float* t = hin; hin = hout; hout = t;
    }

    k_lin12<<<(N + 3) / 4, 256, 0, stream>>>(hin, lin1_W, lin1_b, lin2_W, lin2_b, (float*)d_out, N);
}

// Round 5
// 644.355 us; speedup vs baseline: 2.1778x; 1.0201x over previous
//
#include <hip/hip_runtime.h>
#include <hip/hip_bf16.h>
#include <math.h>

#define HEADS 8
#define EPS 1e-5f

typedef __attribute__((ext_vector_type(8))) _Float16 half8;
typedef __attribute__((ext_vector_type(4))) float f32x4;

__device__ __forceinline__ unsigned short f2h(float f) {
    union { _Float16 h; unsigned short u; } v;
    v.h = (_Float16)f;
    return v.u;
}

// ---------------- CSR build ----------------
__global__ void k_deg(const int* __restrict__ ei, int* __restrict__ deg, int E, int N) {
    int e = blockIdx.x * blockDim.x + threadIdx.x;
    int E2 = E + N;
    if (e >= E2) return;
    int dst = (e < E) ? ei[E + e] : (e - E);
    atomicAdd(&deg[dst], 1);
}

__global__ void k_scan(const int* __restrict__ deg, int* __restrict__ row_ptr, int n) {
    __shared__ int part[1024];
    int t = threadIdx.x;
    int chunk = (n + 1023) >> 10;
    int begin = t * chunk;
    int end = begin + chunk;
    if (begin > n) begin = n;
    if (end > n) end = n;
    int s = 0;
    for (int i = begin; i < end; ++i) s += deg[i];
    part[t] = s;
    __syncthreads();
    for (int off = 1; off < 1024; off <<= 1) {
        int v = (t >= off) ? part[t - off] : 0;
        __syncthreads();
        part[t] += v;
        __syncthreads();
    }
    int run = (t == 0) ? 0 : part[t - 1];
    for (int i = begin; i < end; ++i) { row_ptr[i] = run; run += deg[i]; }
    if (t == 1023) row_ptr[n] = part[1023];
}

__global__ void k_fill(const int* __restrict__ ei, const int* __restrict__ row_ptr,
                       int* __restrict__ fill, int* __restrict__ src_sorted,
                       int* __restrict__ dst_sorted, int E, int N) {
    int e = blockIdx.x * blockDim.x + threadIdx.x;
    int E2 = E + N;
    if (e >= E2) return;
    int srcv, dst;
    if (e < E) { srcv = ei[e]; dst = ei[E + e]; } else { srcv = e - E; dst = srcv; }
    int p = atomicAdd(&fill[dst], 1);
    int pos = row_ptr[dst] + p;
    src_sorted[pos] = srcv;
    dst_sorted[pos] = dst;
}

// ---------------- pack all 6 layers' W into MFMA B-fragment order (fp16) ----------------
__global__ void k_pack(const float* __restrict__ W0, const float* __restrict__ W1,
                       const float* __restrict__ W2, const float* __restrict__ W3,
                       const float* __restrict__ W4, const float* __restrict__ W5,
                       unsigned short* __restrict__ Bp) {
    int idx = blockIdx.x * blockDim.x + threadIdx.x;
    const int CI[6]  = {16, 32, 64, 128, 256, 128};
    const int CO[6]  = {32, 64, 128, 256, 128, 128};
    const int COP[6] = {64, 64, 128, 256, 128, 128};
    const int OFF[7] = {0, 8192, 24576, 90112, 352256, 614400, 745472};
    if (idx >= OFF[6]) return;
    int L = 0;
    while (idx >= OFF[L + 1]) ++L;
    const float* W = L == 0 ? W0 : L == 1 ? W1 : L == 2 ? W2 : L == 3 ? W3 : L == 4 ? W4 : W5;
    int rel = idx - OFF[L];
    int j = rel & 7;
    int lane = (rel >> 3) & 63;
    int t = rel >> 9;
    int nT = COP[L] >> 4;
    int nt = t % nT, kt = t / nT;
    int kk = kt * 32 + ((lane >> 4) << 3) + j;
    int c  = (nt << 4) + (lane & 15);
    int ci = CI[L], co = CO[L];
    float v = 0.f;
    if (c < co) {
        int h = kk / ci, ko = kk % ci;
        v = W[ko * (HEADS * co) + h * co + c];
    }
    Bp[idx] = f2h(v);
}

// ---------------- front: pos BN stats ----------------
__global__ void k_pos_stats(const float* __restrict__ pos, float* __restrict__ stats, int n) {
    int gid = blockIdx.x * blockDim.x + threadIdx.x;
    int stride = gridDim.x * blockDim.x;
    float s0 = 0, s1 = 0, q0 = 0, q1 = 0;
    for (int i = gid; i < n; i += stride) {
        float a = pos[i * 2], b = pos[i * 2 + 1];
        s0 += a; s1 += b; q0 += a * a; q1 += b * b;
    }
    __shared__ float red[256][4];
    int t = threadIdx.x;
    red[t][0] = s0; red[t][1] = s1; red[t][2] = q0; red[t][3] = q1;
    __syncthreads();
    for (int off = 128; off > 0; off >>= 1) {
        if (t < off) {
            red[t][0] += red[t + off][0]; red[t][1] += red[t + off][1];
            red[t][2] += red[t + off][2]; red[t][3] += red[t + off][3];
        }
        __syncthreads();
    }
    if (t == 0) {
        atomicAdd(&stats[0], red[0][0]); atomicAdd(&stats[1], red[0][1]);
        atomicAdd(&stats[2], red[0][2]); atomicAdd(&stats[3], red[0][3]);
    }
}

// ---------------- front: bn(pos) ++ x -> lin0 -> relu -> h0, plus xu0 = h0 @ U0 ----------------
__global__ void k_front(const float* __restrict__ pos, const float* __restrict__ x,
                        const float* __restrict__ stats, const float* __restrict__ g0,
                        const float* __restrict__ b0, const float* __restrict__ W,
                        const float* __restrict__ bias, const float* __restrict__ U0,
                        float* __restrict__ out, float* __restrict__ xu0, int n) {
    int i = blockIdx.x * blockDim.x + threadIdx.x;
    if (i >= n) return;
    float invn = 1.0f / (float)n;
    float in4[4];
    #pragma unroll
    for (int j = 0; j < 2; ++j) {
        float m = stats[j] * invn;
        float v = stats[2 + j] * invn - m * m;
        in4[j] = (pos[i * 2 + j] - m) * rsqrtf(v + EPS) * g0[j] + b0[j];
    }
    in4[2] = x[i * 2]; in4[3] = x[i * 2 + 1];
    float o16[16];
    #pragma unroll
    for (int o = 0; o < 16; ++o) {
        float s = bias[o];
        #pragma unroll
        for (int j = 0; j < 4; ++j) s += in4[j] * W[j * 16 + o];
        o16[o] = fmaxf(s, 0.f);
        out[i * 16 + o] = o16[o];
    }
    #pragma unroll
    for (int hh = 0; hh < 8; ++hh) {
        float p = 0.f;
        #pragma unroll
        for (int k = 0; k < 16; ++k) p += o16[k] * U0[k * 8 + hh];
        xu0[i * 8 + hh] = p;
    }
}

// ---------------- per-edge softmax: Q[e][h] = softmax_h(xu[src]-xu[dst]+c) / deg(dst) ----------------
__global__ void k_qsm(const float* __restrict__ xu, const float* __restrict__ chead,
                      const int* __restrict__ srcs, const int* __restrict__ dsts,
                      const int* __restrict__ row_ptr, float* __restrict__ Q, int E2) {
    int e = blockIdx.x * blockDim.x + threadIdx.x;
    if (e >= E2) return;
    int s = srcs[e], d = dsts[e];
    const float* xs = xu + (size_t)s * 8;
    const float* xd = xu + (size_t)d * 8;
    float t[8], mx = -1e30f;
    #pragma unroll
    for (int h = 0; h < 8; ++h) {
        t[h] = xs[h] - xd[h] + chead[h];
        mx = fmaxf(mx, t[h]);
    }
    float sum = 0.f;
    #pragma unroll
    for (int h = 0; h < 8; ++h) { t[h] = __expf(t[h] - mx); sum += t[h]; }
    float dinv = 1.f / (float)(row_ptr[d + 1] - row_ptr[d]);
    float qs = dinv / sum;
    float* qp = Q + (size_t)e * 8;
    #pragma unroll
    for (int h = 0; h < 8; ++h) qp[h] = t[h] * qs;
}

// ---------------- edge gather: 4 nodes/block, lean FMA loop, fp16 S out ----------------
template<int V>
__global__ __launch_bounds__(256) void k_gather(const float* __restrict__ hin,
        const float* __restrict__ Q, const int* __restrict__ row_ptr,
        const int* __restrict__ srcs, unsigned short* __restrict__ S, int n, int ci) {
    int w = threadIdx.x >> 6, lane = threadIdx.x & 63;
    int i = blockIdx.x * 4 + w;
    if (i >= n) return;
    int rp0 = row_ptr[i], rp1 = row_ptr[i + 1];
    int kb = lane * V;
    bool act = kb < ci;
    float acc[8][V];
    #pragma unroll
    for (int hh = 0; hh < 8; ++hh)
        #pragma unroll
        for (int v = 0; v < V; ++v) acc[hh][v] = 0.f;

    auto body = [&](int e) {
        int s = srcs[e];
        float4 q0 = *(const float4*)(Q + (size_t)e * 8);
        float4 q1 = *(const float4*)(Q + (size_t)e * 8 + 4);
        float q[8] = {q0.x, q0.y, q0.z, q0.w, q1.x, q1.y, q1.z, q1.w};
        float xv[V];
        if (act) {
            const float* hs = hin + (size_t)s * ci + kb;
            if (V == 4) { float4 f = *(const float4*)hs; xv[0] = f.x; xv[1] = f.y; xv[2] = f.z; xv[3] = f.w; }
            else if (V == 2) { float2 f = *(const float2*)hs; xv[0] = f.x; xv[1] = f.y; }
            else xv[0] = hs[0];
        } else {
            #pragma unroll
            for (int v = 0; v < V; ++v) xv[v] = 0.f;
        }
        #pragma unroll
        for (int hh = 0; hh < 8; ++hh)
            #pragma unroll
            for (int v = 0; v < V; ++v) acc[hh][v] += q[hh] * xv[v];
    };

    int e = rp0;
    for (; e + 1 < rp1; e += 2) { body(e); body(e + 1); }
    if (e < rp1) body(e);

    if (act) {
        #pragma unroll
        for (int hh = 0; hh < 8; ++hh) {
            unsigned short o[V];
            #pragma unroll
            for (int v = 0; v < V; ++v) o[v] = f2h(acc[hh][v]);
            unsigned short* sp = S + (size_t)i * 8 * ci + hh * ci + kb;
            if (V == 4)      *(ushort4*)sp = *(ushort4*)o;
            else if (V == 2) *(ushort2*)sp = *(ushort2*)o;
            else             sp[0] = o[0];
        }
    }
}

// ---------------- MFMA fp16 GEMM: C[M,co] (+)= S[M,K] @ Wpacked, LDS-free ----------------
__global__ __launch_bounds__(256) void k_gemm_mfma(const unsigned short* __restrict__ A,
        const unsigned short* __restrict__ Bp, float* __restrict__ C,
        int M, int K, int co, int nT, int kchunk, int atom) {
    int tid = threadIdx.x;
    int w = tid >> 6, lane = tid & 63;
    int quad = lane >> 4, l16 = lane & 15;
    int m0 = blockIdx.x * 64, n0 = blockIdx.y * 64;
    int kb = blockIdx.z * kchunk;
    int m = m0 + w * 16 + l16;
    int mc = m < M ? m : M - 1;
    const half8* Ap = (const half8*)(A + (size_t)mc * K + kb) + quad;
    const half8* Bb = (const half8*)Bp;
    int nt0 = n0 >> 4;
    int kt0 = kb >> 5;
    f32x4 acc[4] = {};
    int nsteps = kchunk >> 5;
    for (int ks = 0; ks < nsteps; ++ks) {
        half8 a = Ap[ks * 4];
        long bbase = ((long)(kt0 + ks) * nT + nt0) * 64 + lane;
        #pragma unroll
        for (int ct = 0; ct < 4; ++ct) {
            half8 b = Bb[bbase + ct * 64];
            acc[ct] = __builtin_amdgcn_mfma_f32_16x16x32_f16(a, b, acc[ct], 0, 0, 0);
        }
    }
    #pragma unroll
    for (int ct = 0; ct < 4; ++ct) {
        #pragma unroll
        for (int r = 0; r < 4; ++r) {
            int row = m0 + w * 16 + quad * 4 + r;
            int col = n0 + ct * 16 + l16;
            if (row < M && col < co) {
                if (atom) atomicAdd(&C[(size_t)row * co + col], acc[ct][r]);
                else C[(size_t)row * co + col] = acc[ct][r];
            }
        }
    }
}

// ---------------- BN stats over nodes ----------------
__global__ void k_stats(const float* __restrict__ z, float* __restrict__ stats, int n, int co) {
    int tid = threadIdx.x;
    long total = (long)n * co;
    long stride = (long)gridDim.x * blockDim.x;
    long start = (long)blockIdx.x * blockDim.x + tid;
    float s = 0.f, q = 0.f;
    for (long idx = start; idx < total; idx += stride) {
        float v = z[idx];
        s += v; q += v * v;
    }
    __shared__ float ls[256], lq[256];
    ls[tid] = s; lq[tid] = q;
    __syncthreads();
    for (int off = 128; off >= co; off >>= 1) {
        if (tid < off) { ls[tid] += ls[tid + off]; lq[tid] += lq[tid + off]; }
        __syncthreads();
    }
    if (tid < co) {
        atomicAdd(&stats[tid], ls[tid]);
        atomicAdd(&stats[co + tid], lq[tid]);
    }
}

// ---------------- fused BN apply + relu + next-layer xu (wave per node) ----------------
template<int V>
__global__ __launch_bounds__(256) void k_bnx(const float* __restrict__ z,
        const float* __restrict__ stats, const float* __restrict__ g,
        const float* __restrict__ b, const float* __restrict__ Un,
        float* __restrict__ hout, float* __restrict__ xun, int n, int co) {
    int w = threadIdx.x >> 6, lane = threadIdx.x & 63;
    int node = blockIdx.x * 4 + w;
    if (node >= n) return;
    int c0 = lane * V;
    bool act = c0 < co;
    float invn = 1.f / (float)n;
    float hv[V];
    #pragma unroll
    for (int v = 0; v < V; ++v) hv[v] = 0.f;
    if (act) {
        const float* zp = z + (size_t)node * co + c0;
        float zv[V];
        if (V == 4) { float4 f = *(const float4*)zp; zv[0] = f.x; zv[1] = f.y; zv[2] = f.z; zv[3] = f.w; }
        else if (V == 2) { float2 f = *(const float2*)zp; zv[0] = f.x; zv[1] = f.y; }
        else zv[0] = zp[0];
        #pragma unroll
        for (int v = 0; v < V; ++v) {
            int cch = c0 + v;
            float mm = stats[cch] * invn;
            float vr = stats[co + cch] * invn - mm * mm;
            hv[v] = fmaxf((zv[v] - mm) * rsqrtf(vr + EPS) * g[cch] + b[cch], 0.f);
        }
        float* hp = hout + (size_t)node * co + c0;
        if (V == 4) { float4 f = {hv[0], hv[1], hv[2], hv[3]}; *(float4*)hp = f; }
        else if (V == 2) { float2 f = {hv[0], hv[1]}; *(float2*)hp = f; }
        else hp[0] = hv[0];
    }
    if (Un) {
        float p[8];
        #pragma unroll
        for (int hh = 0; hh < 8; ++hh) p[hh] = 0.f;
        if (act) {
            #pragma unroll
            for (int v = 0; v < V; ++v)
                #pragma unroll
                for (int hh = 0; hh < 8; ++hh) p[hh] += hv[v] * Un[(c0 + v) * 8 + hh];
        }
        #pragma unroll
        for (int hh = 0; hh < 8; ++hh) {
            #pragma unroll
            for (int off = 32; off; off >>= 1) p[hh] += __shfl_xor(p[hh], off, 64);
        }
        float mine = 0.f;
        #pragma unroll
        for (int hh = 0; hh < 8; ++hh) if (lane == hh) mine = p[hh];
        if (lane < 8) xun[node * 8 + lane] = mine;
    }
}

// ---------------- fused lin1(relu) + lin2: one wave per node ----------------
__global__ __launch_bounds__(256) void k_lin12(const float* __restrict__ h,
                                               const float* __restrict__ W1,
                                               const float* __restrict__ b1,
                                               const float* __restrict__ W2,
                                               const float* __restrict__ b2,
                                               float* __restrict__ out, int n) {
    int lane = threadIdx.x & 63;
    int node = blockIdx.x * 4 + (threadIdx.x >> 6);
    if (node >= n) return;
    const float* hr = h + (size_t)node * 128;
    float s = b1[lane];
    #pragma unroll 8
    for (int k = 0; k < 128; ++k) s += hr[k] * W1[k * 64 + lane];
    float r = fmaxf(s, 0.f);
    float p0 = r * W2[lane * 2];
    float p1 = r * W2[lane * 2 + 1];
    #pragma unroll
    for (int off = 32; off > 0; off >>= 1) {
        p0 += __shfl_down(p0, off, 64);
        p1 += __shfl_down(p1, off, 64);
    }
    if (lane == 0) {
        out[node * 2] = p0 + b2[0];
        out[node * 2 + 1] = p1 + b2[1];
    }
}

extern "C" void kernel_launch(void* const* d_in, const int* in_sizes, int n_in,
                              void* d_out, int out_size, void* d_ws, size_t ws_size,
                              hipStream_t stream) {
    const float* pos    = (const float*)d_in[0];
    const float* x      = (const float*)d_in[1];
    const int*   ei     = (const int*)d_in[2];
    const float* g0     = (const float*)d_in[3];
    const float* b0     = (const float*)d_in[4];
    const float* lin0_W = (const float*)d_in[5];
    const float* lin0_b = (const float*)d_in[6];
    const float* lin1_W = (const float*)d_in[43];
    const float* lin1_b = (const float*)d_in[44];
    const float* lin2_W = (const float*)d_in[45];
    const float* lin2_b = (const float*)d_in[46];

    int N = in_sizes[0] / 2;
    int E = in_sizes[2] / 2;
    int E2 = E + N;

    static const int CI[6]  = {16, 32, 64, 128, 256, 128};
    static const int CO[6]  = {32, 64, 128, 256, 128, 128};
    static const int COP[6] = {64, 64, 128, 256, 128, 128};
    static const int KS[6]  = {4, 4, 2, 1, 2, 2};
    static const int BPOFF[6] = {0, 8192, 24576, 90112, 352256, 614400};

    char* p = (char*)d_ws;
    auto alloc = [&](size_t bytes) -> char* {
        char* r = p;
        p += (bytes + 255) & ~(size_t)255;
        return r;
    };
    unsigned short* BpAll = (unsigned short*)alloc(745472ull * 2);
    char* zr = alloc(((size_t)2 * N + 4 + 6 * 512) * 4);
    int*   deg      = (int*)zr;
    int*   fill     = deg + N;
    float* pstats   = (float*)(fill + N);
    float* statsAll = pstats + 4;
    size_t zr_bytes = ((size_t)2 * N + 4 + 6 * 512) * 4;

    int* row_ptr    = (int*)alloc(((size_t)N + 1) * 4);
    int* src_sorted = (int*)alloc((size_t)E2 * 4);
    int* dst_sorted = (int*)alloc((size_t)E2 * 4);
    float* xu       = (float*)alloc((size_t)N * 8 * 4);
    float* Q        = (float*)alloc((size_t)E2 * 8 * 4);
    unsigned short* S = (unsigned short*)alloc((size_t)N * 2048 * 2);
    float* z        = (float*)alloc((size_t)N * 256 * 4);
    float* hA       = (float*)alloc((size_t)N * 256 * 4);
    float* hB       = (float*)alloc((size_t)N * 256 * 4);

    hipMemsetAsync(zr, 0, zr_bytes, stream);

    const int tpb = 256;
    k_deg<<<(E2 + tpb - 1) / tpb, tpb, 0, stream>>>(ei, deg, E, N);
    k_scan<<<1, 1024, 0, stream>>>(deg, row_ptr, N);
    k_fill<<<(E2 + tpb - 1) / tpb, tpb, 0, stream>>>(ei, row_ptr, fill, src_sorted, dst_sorted, E, N);
    k_pack<<<(745472 + tpb - 1) / tpb, tpb, 0, stream>>>(
        (const float*)d_in[7], (const float*)d_in[13], (const float*)d_in[19],
        (const float*)d_in[25], (const float*)d_in[31], (const float*)d_in[37], BpAll);
    k_pos_stats<<<64, 256, 0, stream>>>(pos, pstats, N);
    k_front<<<(N + tpb - 1) / tpb, tpb, 0, stream>>>(pos, x, pstats, g0, b0, lin0_W, lin0_b,
                                                     (const float*)d_in[8], hA, xu, N);

    float* hin = hA;
    float* hout = hB;
    for (int L = 0; L < 6; ++L) {
        int ci = CI[L], co = CO[L], coP = COP[L];
        const float* Ch = (const float*)d_in[7 + L * 6 + 2];
        const float* gc = (const float*)d_in[7 + L * 6 + 4];
        const float* bc = (const float*)d_in[7 + L * 6 + 5];
        const float* Un = (L < 5) ? (const float*)d_in[7 + (L + 1) * 6 + 1] : nullptr;
        int K = HEADS * ci;
        float* statsL = statsAll + L * 512;

        k_qsm<<<(E2 + tpb - 1) / tpb, tpb, 0, stream>>>(xu, Ch, src_sorted, dst_sorted, row_ptr, Q, E2);

        int ggrid = (N + 3) / 4;
        if (ci >= 256)      k_gather<4><<<ggrid, 256, 0, stream>>>(hin, Q, row_ptr, src_sorted, S, N, ci);
        else if (ci >= 128) k_gather<2><<<ggrid, 256, 0, stream>>>(hin, Q, row_ptr, src_sorted, S, N, ci);
        else                k_gather<1><<<ggrid, 256, 0, stream>>>(hin, Q, row_ptr, src_sorted, S, N, ci);

        int atom = KS[L] > 1;
        if (atom) hipMemsetAsync(z, 0, (size_t)N * co * 4, stream);
        dim3 g((N + 63) / 64, coP / 64, KS[L]);
        k_gemm_mfma<<<g, 256, 0, stream>>>(S, BpAll + BPOFF[L], z, N, K, co, coP / 16, K / KS[L], atom);

        k_stats<<<256, 256, 0, stream>>>(z, statsL, N, co);

        int bgrid = (N + 3) / 4;
        if (co >= 256)      k_bnx<4><<<bgrid, 256, 0, stream>>>(z, statsL, gc, bc, Un, hout, xu, N, co);
        else if (co >= 128) k_bnx<2><<<bgrid, 256, 0, stream>>>(z, statsL, gc, bc, Un, hout, xu, N, co);
        else                k_bnx<1><<<bgrid, 256, 0, stream>>>(z, statsL, gc, bc, Un, hout, xu, N, co);

        float* t = hin; hin = hout; hout = t;
    }

    k_lin12<<<(N + 3) / 4, 256, 0, stream>>>(hin, lin1_W, lin1_b, lin2_W, lin2_b, (float*)d_out, N);
}